// Round 7
// baseline (838.170 us; speedup 1.0000x reference)
//
#include <hip/hip_runtime.h>
#include <math.h>

#define NT 730
#define NS 2000
#define NH 16
#define NG 32
#define NR 15
#define HID 256
#define NSNH 32000

// 2*log2(e): pre-folded into BASE12/CC4 so tanh arg is a bare fma
// and tanh(x) = 1 - 2*rcp(exp2(y)+1), y = SC*x.
#define SC 2.885390081777927f
#define INV6 0.16666666666666666f

typedef _Float16 f16x8 __attribute__((ext_vector_type(8)));
typedef __fp16 fp16v2 __attribute__((ext_vector_type(2)));   // cvt_pkrtz native return type
typedef float f32x4 __attribute__((ext_vector_type(4)));

__device__ __forceinline__ float tanh_pre(float y) {   // y = SC * x
    float e = __builtin_amdgcn_exp2f(y);
    float r = __builtin_amdgcn_rcpf(e + 1.f);
    return fmaf(-2.f, r, 1.f);
}
__device__ __forceinline__ float fast_tanh(float x) { return tanh_pre(x * SC); }
__device__ __forceinline__ float sigmoidf_(float x) { return 1.f / (1.f + __expf(-x)); }

__device__ __forceinline__ f16x8 tanh8(float4 lo, float4 hi) {
    union { fp16v2 h[4]; f16x8 v; } u;
    u.h[0] = __builtin_amdgcn_cvt_pkrtz(tanh_pre(lo.x), tanh_pre(lo.y));
    u.h[1] = __builtin_amdgcn_cvt_pkrtz(tanh_pre(lo.z), tanh_pre(lo.w));
    u.h[2] = __builtin_amdgcn_cvt_pkrtz(tanh_pre(hi.x), tanh_pre(hi.y));
    u.h[3] = __builtin_amdgcn_cvt_pkrtz(tanh_pre(hi.z), tanh_pre(hi.w));
    return u.v;
}

// ---------------------------------------------------------------------------
// k_pack: CC4[k] = (SC*a1, SC*c0, SC*c1, SC*c2) interleaved float4.
//   W2H folding: cols 0..31 x1/6 (hsig->clamp); cols 32..47 xSC (exp->exp2).
// ---------------------------------------------------------------------------
__global__ __launch_bounds__(256) void k_pack(
    const float* __restrict__ T1W1, const float* __restrict__ T2W1,
    const float* __restrict__ T1W2, const float* __restrict__ T2W2,
    float4* __restrict__ CC4, _Float16* __restrict__ W2H)
{
    int k = threadIdx.x;
    CC4[k] = make_float4(SC * T1W1[k * (1 + NG)],
                         SC * T2W1[k * (3 + NG)],
                         SC * T2W1[k * (3 + NG) + 1],
                         SC * T2W1[k * (3 + NG) + 2]);
    for (int c = 0; c < 48; ++c) {
        float w = (c < 32) ? (INV6 * T1W2[c * HID + k]) : (SC * T2W2[(c - 32) * HID + k]);
        W2H[c * HID + k] = (_Float16)w;
    }
}

// ---------------------------------------------------------------------------
// k_basin: 4 basins per block; BASE12[s][k] = (SC*b1, SC*b2) interleaved.
// ---------------------------------------------------------------------------
__global__ __launch_bounds__(256) void k_basin(
    const float* __restrict__ XC,
    const float* __restrict__ fcW1, const float* __restrict__ fcb1,
    const float* __restrict__ fcW2, const float* __restrict__ fcb2,
    const float* __restrict__ fRW1, const float* __restrict__ fRb1,
    const float* __restrict__ fRW2, const float* __restrict__ fRb2,
    const float* __restrict__ T1W1, const float* __restrict__ T1b1,
    const float* __restrict__ T2W1, const float* __restrict__ T2b1,
    float* __restrict__ P8, float* __restrict__ RKGA,
    float2* __restrict__ BASE12)
{
    const int s0 = blockIdx.x * 4, tid = threadIdx.x;
    __shared__ float xcs[4][NG];
    __shared__ float h[4][HID], hR[4][HID];
    __shared__ float wbuf[4][10 * NH], wRbuf[4][NH * NR];
    __shared__ float gav[4][NH];

    if (tid < 128) xcs[tid >> 5][tid & 31] = XC[(s0 + (tid >> 5)) * NG + (tid & 31)];
    __syncthreads();

    {
        float ab0 = fcb1[tid], ab1 = ab0, ab2 = ab0, ab3 = ab0;
        float rb0 = fRb1[tid], rb1 = rb0, rb2 = rb0, rb3 = rb0;
        const float4* w4  = (const float4*)(fcW1 + tid * NG);
        const float4* wR4 = (const float4*)(fRW1 + tid * NG);
#pragma unroll
        for (int g = 0; g < NG / 4; ++g) {
            float4 wv = w4[g], rv = wR4[g];
            float4 x0 = *(const float4*)&xcs[0][g * 4];
            float4 x1 = *(const float4*)&xcs[1][g * 4];
            float4 x2 = *(const float4*)&xcs[2][g * 4];
            float4 x3 = *(const float4*)&xcs[3][g * 4];
            ab0 += x0.x*wv.x + x0.y*wv.y + x0.z*wv.z + x0.w*wv.w;
            ab1 += x1.x*wv.x + x1.y*wv.y + x1.z*wv.z + x1.w*wv.w;
            ab2 += x2.x*wv.x + x2.y*wv.y + x2.z*wv.z + x2.w*wv.w;
            ab3 += x3.x*wv.x + x3.y*wv.y + x3.z*wv.z + x3.w*wv.w;
            rb0 += x0.x*rv.x + x0.y*rv.y + x0.z*rv.z + x0.w*rv.w;
            rb1 += x1.x*rv.x + x1.y*rv.y + x1.z*rv.z + x1.w*rv.w;
            rb2 += x2.x*rv.x + x2.y*rv.y + x2.z*rv.z + x2.w*rv.w;
            rb3 += x3.x*rv.x + x3.y*rv.y + x3.z*rv.z + x3.w*rv.w;
        }
        h[0][tid] = fast_tanh(ab0); h[1][tid] = fast_tanh(ab1);
        h[2][tid] = fast_tanh(ab2); h[3][tid] = fast_tanh(ab3);
        hR[0][tid] = fast_tanh(rb0); hR[1][tid] = fast_tanh(rb1);
        hR[2][tid] = fast_tanh(rb2); hR[3][tid] = fast_tanh(rb3);

        float b10 = T1b1[tid], b11 = b10, b12 = b10, b13 = b10;
        float b20 = T2b1[tid], b21 = b20, b22 = b20, b23 = b20;
        const float* w1 = T1W1 + tid * (1 + NG) + 1;
        const float* w2 = T2W1 + tid * (3 + NG) + 3;
#pragma unroll 8
        for (int g = 0; g < NG; ++g) {
            float w1g = w1[g], w2g = w2[g];
            float x0 = xcs[0][g], x1 = xcs[1][g], x2 = xcs[2][g], x3 = xcs[3][g];
            b10 = fmaf(x0, w1g, b10); b11 = fmaf(x1, w1g, b11);
            b12 = fmaf(x2, w1g, b12); b13 = fmaf(x3, w1g, b13);
            b20 = fmaf(x0, w2g, b20); b21 = fmaf(x1, w2g, b21);
            b22 = fmaf(x2, w2g, b22); b23 = fmaf(x3, w2g, b23);
        }
        BASE12[(size_t)(s0 + 0) * HID + tid] = make_float2(SC * b10, SC * b20);
        BASE12[(size_t)(s0 + 1) * HID + tid] = make_float2(SC * b11, SC * b21);
        BASE12[(size_t)(s0 + 2) * HID + tid] = make_float2(SC * b12, SC * b22);
        BASE12[(size_t)(s0 + 3) * HID + tid] = make_float2(SC * b13, SC * b23);
    }
    __syncthreads();

    if (tid < 10 * NH) {
        float a0 = fcb2[tid], a1 = a0, a2 = a0, a3 = a0;
        const float4* w4 = (const float4*)(fcW2 + tid * HID);
        for (int k = 0; k < HID / 4; ++k) {
            float4 wv = w4[k];
            float4 h0 = *(const float4*)&h[0][k * 4];
            float4 h1 = *(const float4*)&h[1][k * 4];
            float4 h2 = *(const float4*)&h[2][k * 4];
            float4 h3 = *(const float4*)&h[3][k * 4];
            a0 += h0.x*wv.x + h0.y*wv.y + h0.z*wv.z + h0.w*wv.w;
            a1 += h1.x*wv.x + h1.y*wv.y + h1.z*wv.z + h1.w*wv.w;
            a2 += h2.x*wv.x + h2.y*wv.y + h2.z*wv.z + h2.w*wv.w;
            a3 += h3.x*wv.x + h3.y*wv.y + h3.z*wv.z + h3.w*wv.w;
        }
        wbuf[0][tid] = a0; wbuf[1][tid] = a1; wbuf[2][tid] = a2; wbuf[3][tid] = a3;
    }
    if (tid < NH * NR) {
        float a0 = fRb2[tid], a1 = a0, a2 = a0, a3 = a0;
        const float4* w4 = (const float4*)(fRW2 + tid * HID);
        for (int k = 0; k < HID / 4; ++k) {
            float4 wv = w4[k];
            float4 h0 = *(const float4*)&hR[0][k * 4];
            float4 h1 = *(const float4*)&hR[1][k * 4];
            float4 h2 = *(const float4*)&hR[2][k * 4];
            float4 h3 = *(const float4*)&hR[3][k * 4];
            a0 += h0.x*wv.x + h0.y*wv.y + h0.z*wv.z + h0.w*wv.w;
            a1 += h1.x*wv.x + h1.y*wv.y + h1.z*wv.z + h1.w*wv.w;
            a2 += h2.x*wv.x + h2.y*wv.y + h2.z*wv.z + h2.w*wv.w;
            a3 += h3.x*wv.x + h3.y*wv.y + h3.z*wv.z + h3.w*wv.w;
        }
        wRbuf[0][tid] = a0; wRbuf[1][tid] = a1; wRbuf[2][tid] = a2; wRbuf[3][tid] = a3;
    }
    __syncthreads();

    if (tid < 64) {
        int b = tid >> 4, hh = tid & 15;
        const float* wb = wbuf[b];
        float mx = -1e30f;
        for (int i = 0; i < NH; ++i) mx = fmaxf(mx, wb[6 * NH + i]);
        float sum = 0.f;
        for (int i = 0; i < NH; ++i) sum += expf(wb[6 * NH + i] - mx);
        gav[b][hh] = expf(wb[6 * NH + hh] - mx) / sum;

        float* p = P8 + (size_t)((s0 + b) * NH + hh) * 8;
        p[0] = sigmoidf_(wb[1 * NH + hh]);
        p[1] = sigmoidf_(wb[2 * NH + hh]);
        p[2] = sigmoidf_(wb[3 * NH + hh]);
        p[3] = sigmoidf_(wb[4 * NH + hh]) * 0.1f;
        p[4] = expf(wb[5 * NH + hh]) * 2.f;
        p[5] = fmaxf(wb[7 * NH + hh], 0.f);
        p[6] = fmaxf(wb[8 * NH + hh], 0.f);
        p[7] = fmaxf(wb[9 * NH + hh], 0.f);
    }
    __syncthreads();

    for (int it = tid; it < 4 * NH * NR; it += 256) {
        int b = it / (NH * NR), r = it % (NH * NR);
        int hh = r / NR, j = r % NR;
        RKGA[(size_t)((s0 + b) * NH + hh) * 16 + (NR - 1 - j)] =
            gav[b][hh] * fmaxf(wRbuf[b][hh * NR + j], 0.f);
    }
}

// ---------------------------------------------------------------------------
// PSE helper (vp partition).
// ---------------------------------------------------------------------------
__device__ __forceinline__ void store_pse(float4* __restrict__ PSE, long m, float2 pe, float2 t12) {
    float P = pe.x, E = pe.y, T1 = t12.x, T2 = t12.y;
    float den = T2 - T1;
    float ratio = (T1 + T2) / ((den == 0.f) ? 1.f : den);
    ratio = fminf(fmaxf(ratio, -1.f), 1.f);
    if ((T1 >= 0.f) || (T2 <= 0.f)) ratio = 0.f;
    float vp = 1.f - acosf(ratio) * (1.f / 3.1415f);
    if (T1 >= 0.f) vp = 1.f;
    if (T2 <= 0.f) vp = 0.f;
    PSE[m] = make_float4(P * (1.f - vp), P * vp, E, 0.f);
}

// ---------------------------------------------------------------------------
// k_mlp v6: one wave per block (wave-granular scheduling), t-reuse x4,
//   CC4/BASE12 interleaved single-base loads, no private arrays.
// ---------------------------------------------------------------------------
__global__ __launch_bounds__(64) void k_mlp(
    const float* __restrict__ X,
    const float2* __restrict__ BASE12, const float4* __restrict__ CC4,
    const _Float16* __restrict__ W2H,
    const float* __restrict__ T1b2, const float* __restrict__ T2b2,
    uint2* __restrict__ VMK, float4* __restrict__ PSE)
{
    const int lane = threadIdx.x;
    const int quad = lane >> 4, ml = lane & 15;
    const int s0 = blockIdx.x * 16;
    const int t0 = blockIdx.y * 4;
    const int srow = s0 + ml;

    const int tc0 = (t0 < NT) ? t0 : (NT - 1);
    const int tc1 = (t0 + 1 < NT) ? t0 + 1 : (NT - 1);
    const int tc2 = (t0 + 2 < NT) ? t0 + 2 : (NT - 1);
    const int tc3 = (t0 + 3 < NT) ? t0 + 3 : (NT - 1);

    const float* xr0 = X + ((long)tc0 * NS + srow) * 6;
    const float* xr1 = X + ((long)tc1 * NS + srow) * 6;
    const float* xr2 = X + ((long)tc2 * NS + srow) * 6;
    const float* xr3 = X + ((long)tc3 * NS + srow) * 6;
    float2 tt0 = *(const float2*)(xr0 + 2), rl0 = *(const float2*)(xr0 + 4);
    float2 tt1 = *(const float2*)(xr1 + 2), rl1 = *(const float2*)(xr1 + 4);
    float2 tt2 = *(const float2*)(xr2 + 2), rl2 = *(const float2*)(xr2 + 4);
    float2 tt3 = *(const float2*)(xr3 + 2), rl3 = *(const float2*)(xr3 + 4);

    const float bvi = fmaf(T1b2[ml], INV6, 0.5f);
    const float bvk = fmaf(T1b2[NH + ml], INV6, 0.5f);
    const float bvm = SC * T2b2[ml];
    f32x4 ac0_0 = {bvi, bvi, bvi, bvi}, ac0_1 = ac0_0, ac0_2 = ac0_0, ac0_3 = ac0_0;
    f32x4 ac1_0 = {bvk, bvk, bvk, bvk}, ac1_1 = ac1_0, ac1_2 = ac1_0, ac1_3 = ac1_0;
    f32x4 ac2_0 = {bvm, bvm, bvm, bvm}, ac2_1 = ac2_0, ac2_2 = ac2_0, ac2_3 = ac2_0;

    const float2* b12p = BASE12 + (size_t)srow * HID;
    const _Float16* wvi = W2H + (size_t)ml * HID;
    const _Float16* wvk = W2H + (size_t)(NH + ml) * HID;
    const _Float16* wvm = W2H + (size_t)(2 * NH + ml) * HID;

#pragma unroll 2
    for (int ks = 0; ks < 8; ++ks) {
        const int kb = ks * 32 + quad * 8;
        float4 cc0 = CC4[kb], cc1 = CC4[kb + 1], cc2 = CC4[kb + 2], cc3 = CC4[kb + 3];
        float4 cc4 = CC4[kb + 4], cc5 = CC4[kb + 5], cc6 = CC4[kb + 6], cc7 = CC4[kb + 7];
        float4 bA = *(const float4*)(b12p + kb);       // b1[k],b2[k],b1[k+1],b2[k+1]
        float4 bB = *(const float4*)(b12p + kb + 2);
        float4 bC = *(const float4*)(b12p + kb + 4);
        float4 bD = *(const float4*)(b12p + kb + 6);
        f16x8 Bvi = *(const f16x8*)(wvi + kb);
        f16x8 Bvk = *(const f16x8*)(wvk + kb);
        f16x8 Bvm = *(const f16x8*)(wvm + kb);

#define ARG2(CC, B2, TT, RL) fmaf(TT.y, CC.w, fmaf(TT.x, CC.z, fmaf(RL.x, CC.y, B2)))
#define DO_TILE(RL, TT, AC0, AC1, AC2) { \
        float4 a1lo = make_float4(fmaf(RL.y, cc0.x, bA.x), fmaf(RL.y, cc1.x, bA.z), \
                                  fmaf(RL.y, cc2.x, bB.x), fmaf(RL.y, cc3.x, bB.z)); \
        float4 a1hi = make_float4(fmaf(RL.y, cc4.x, bC.x), fmaf(RL.y, cc5.x, bC.z), \
                                  fmaf(RL.y, cc6.x, bD.x), fmaf(RL.y, cc7.x, bD.z)); \
        f16x8 Af1 = tanh8(a1lo, a1hi); \
        float4 a2lo = make_float4(ARG2(cc0, bA.y, TT, RL), ARG2(cc1, bA.w, TT, RL), \
                                  ARG2(cc2, bB.y, TT, RL), ARG2(cc3, bB.w, TT, RL)); \
        float4 a2hi = make_float4(ARG2(cc4, bC.y, TT, RL), ARG2(cc5, bC.w, TT, RL), \
                                  ARG2(cc6, bD.y, TT, RL), ARG2(cc7, bD.w, TT, RL)); \
        f16x8 Af2 = tanh8(a2lo, a2hi); \
        AC0 = __builtin_amdgcn_mfma_f32_16x16x32_f16(Af1, Bvi, AC0, 0, 0, 0); \
        AC1 = __builtin_amdgcn_mfma_f32_16x16x32_f16(Af1, Bvk, AC1, 0, 0, 0); \
        AC2 = __builtin_amdgcn_mfma_f32_16x16x32_f16(Af2, Bvm, AC2, 0, 0, 0); }

        DO_TILE(rl0, tt0, ac0_0, ac1_0, ac2_0)
        DO_TILE(rl1, tt1, ac0_1, ac1_1, ac2_1)
        DO_TILE(rl2, tt2, ac0_2, ac1_2, ac2_2)
        DO_TILE(rl3, tt3, ac0_3, ac1_3, ac2_3)
#undef DO_TILE
#undef ARG2
    }

#define EPI(TC, AC0, AC1, AC2) { \
    long rowbase = (long)TC * NS + s0 + quad * 4; \
    _Pragma("unroll") \
    for (int rg = 0; rg < 4; ++rg) { \
        float vi = fminf(fmaxf(AC0[rg], 0.f), 1.f); \
        float vk = fminf(fmaxf(AC1[rg], 0.f), 1.f); \
        float vm = __builtin_amdgcn_exp2f(AC2[rg]); \
        unsigned pk = (unsigned)(vi * 65535.f + 0.5f) | ((unsigned)(vk * 65535.f + 0.5f) << 16); \
        VMK[(rowbase + rg) * NH + ml] = make_uint2(pk, __float_as_uint(vm)); \
    } }

    EPI(tc0, ac0_0, ac1_0, ac2_0)
    EPI(tc1, ac0_1, ac1_1, ac2_1)
    EPI(tc2, ac0_2, ac1_2, ac2_2)
    EPI(tc3, ac0_3, ac1_3, ac2_3)
#undef EPI

    {
        int tq = t0 + quad; if (tq >= NT) tq = NT - 1;
        const float* xq = X + ((long)tq * NS + srow) * 6;
        float2 peq = *(const float2*)xq;
        float2 ttq = *(const float2*)(xq + 2);
        store_pse(PSE, (long)tq * NS + srow, peq, ttq);
    }
}

// ---------------------------------------------------------------------------
// k_scan v3: bare 730-step recurrence; stores qt[t,ch] (fp16). Conv+reduce
//   moved to k_conv (they were ~300 cyc/step of serial shuffle chain here).
// ---------------------------------------------------------------------------
__global__ __launch_bounds__(64) void k_scan(
    const uint2* __restrict__ VMK, const float4* __restrict__ PSE,
    const float* __restrict__ P8, _Float16* __restrict__ QT)
{
    int lane = threadIdx.x;
    int s = blockIdx.x * 4 + (lane >> 4);
    int hh = lane & 15;
    size_t ch = (size_t)s * NH + hh;

    const float4* pp = (const float4*)(P8 + (size_t)ch * 8);
    float4 pa = pp[0], pb4 = pp[1];
    float k1 = pa.x, k2 = pa.y, k23 = pa.z, k3 = pa.w;
    float gl = pb4.x, qb = pb4.y, ge1 = pb4.z, ge2 = pb4.w;

    float S0 = 0.f, Sv = 0.f, S2 = 0.f, S3 = 0.f;

    uint2 vb[14]; float4 pbf[14];
#pragma unroll
    for (int i = 0; i < 14; ++i) {
        vb[i] = VMK[(size_t)i * NSNH + ch];
        pbf[i] = PSE[(size_t)i * NS + s];
    }

    int t = 0;
#define SBODY(I) { \
    uint2 v = vb[I]; float4 ps = pbf[I]; \
    int t2 = t + 14; if (t2 > NT - 1) t2 = NT - 1; \
    vb[I] = VMK[(size_t)t2 * NSNH + ch]; \
    pbf[I] = PSE[(size_t)t2 * NS + s]; \
    float vi = (float)(v.x & 0xffffu) * (1.f / 65535.f); \
    float vk = (float)(v.x >> 16) * (1.f / 65535.f); \
    float vm = __uint_as_float(v.y); \
    float Ps = ps.x, Pl = ps.y, E = ps.z; \
    float H0 = S0 + Ps; \
    float qSm = fminf(H0, vm); S0 = H0 - qSm; \
    float Hv = fmaxf(Sv + Pl * (1.f - vi) - E * ge1, 0.f); \
    float qv = Sv * vk; Sv = Hv - qv; \
    float H2 = fmaxf(S2 + qSm + qv - E * ge2 + Pl * vi, 0.f); \
    float x1 = H2 - gl; \
    float Q1 = (x1 > 0.f) ? __expf(k1 * __logf(x1)) : 0.f; \
    float q2 = fminf(H2, gl) * k2; \
    float Q2 = q2 * (1.f - k23); \
    float H3 = S3 + q2 * k23; \
    float Q3 = H3 * k3 + qb; \
    S2 = H2 - Q1 - q2; S3 = H3 - Q3; \
    QT[(size_t)t * NSNH + ch] = (_Float16)(Q1 + Q2 + Q3); \
    ++t; }

    for (int tb = 0; tb < 52; ++tb) {          // 52 * 14 = 728 steps
        SBODY(0) SBODY(1) SBODY(2) SBODY(3) SBODY(4) SBODY(5) SBODY(6)
        SBODY(7) SBODY(8) SBODY(9) SBODY(10) SBODY(11) SBODY(12) SBODY(13)
    }
    SBODY(0) SBODY(1)                          // steps 728, 729
#undef SBODY
}

// ---------------------------------------------------------------------------
// k_conv: OUT[t,s] = sum_{h,d} rk[s,h,d] * qt[t-d,s,h]  (rk includes ga).
//   Block = one s x 256 consecutive t. rk transposed to LDS [d][h] (broadcast
//   reads); qt rows shared across neighboring-t lanes via L1.
// ---------------------------------------------------------------------------
__global__ __launch_bounds__(256) void k_conv(
    const _Float16* __restrict__ QT, const float* __restrict__ RKGA,
    float* __restrict__ OUT)
{
    const int s = blockIdx.x;
    const int tid = threadIdx.x;
    const int t = blockIdx.y * 256 + tid;

    __shared__ float rks[16][16];   // [d][h]
    // RKGA[s*256 + h*16 + d] -> rks[d][h]
    rks[tid & 15][tid >> 4] = RKGA[(size_t)s * 256 + tid];
    __syncthreads();

    if (t >= NT) return;

    const _Float16* qbase = QT + (size_t)s * NH;
    float acc = 0.f;
#pragma unroll
    for (int d = 0; d < 15; ++d) {
        int ts = t - d;
        float4 r0 = *(const float4*)&rks[d][0];
        float4 r1 = *(const float4*)&rks[d][4];
        float4 r2 = *(const float4*)&rks[d][8];
        float4 r3 = *(const float4*)&rks[d][12];
        if (ts >= 0) {
            const _Float16* q = qbase + (size_t)ts * NSNH;
            f16x8 qa = *(const f16x8*)q;
            f16x8 qb8 = *(const f16x8*)(q + 8);
            acc = fmaf((float)qa[0], r0.x, acc);
            acc = fmaf((float)qa[1], r0.y, acc);
            acc = fmaf((float)qa[2], r0.z, acc);
            acc = fmaf((float)qa[3], r0.w, acc);
            acc = fmaf((float)qa[4], r1.x, acc);
            acc = fmaf((float)qa[5], r1.y, acc);
            acc = fmaf((float)qa[6], r1.z, acc);
            acc = fmaf((float)qa[7], r1.w, acc);
            acc = fmaf((float)qb8[0], r2.x, acc);
            acc = fmaf((float)qb8[1], r2.y, acc);
            acc = fmaf((float)qb8[2], r2.z, acc);
            acc = fmaf((float)qb8[3], r2.w, acc);
            acc = fmaf((float)qb8[4], r3.x, acc);
            acc = fmaf((float)qb8[5], r3.y, acc);
            acc = fmaf((float)qb8[6], r3.z, acc);
            acc = fmaf((float)qb8[7], r3.w, acc);
        }
    }
    OUT[(size_t)t * NS + s] = acc;
}

// ---------------------------------------------------------------------------
extern "C" void kernel_launch(void* const* d_in, const int* in_sizes, int n_in,
                              void* d_out, int out_size, void* d_ws, size_t ws_size,
                              hipStream_t stream)
{
    const float* X    = (const float*)d_in[0];
    const float* XC   = (const float*)d_in[1];
    const float* fcW1 = (const float*)d_in[2];
    const float* fcb1 = (const float*)d_in[3];
    const float* fcW2 = (const float*)d_in[4];
    const float* fcb2 = (const float*)d_in[5];
    const float* fRW1 = (const float*)d_in[6];
    const float* fRb1 = (const float*)d_in[7];
    const float* fRW2 = (const float*)d_in[8];
    const float* fRb2 = (const float*)d_in[9];
    const float* T1W1 = (const float*)d_in[10];
    const float* T1b1 = (const float*)d_in[11];
    const float* T1W2 = (const float*)d_in[12];
    const float* T1b2 = (const float*)d_in[13];
    const float* T2W1 = (const float*)d_in[14];
    const float* T2b1 = (const float*)d_in[15];
    const float* T2W2 = (const float*)d_in[16];
    const float* T2b2 = (const float*)d_in[17];
    float* OUT = (float*)d_out;

    char* w = (char*)d_ws;
    uint2* VMK     = (uint2*)w;     w += (size_t)NT * NSNH * 8;     // 186.9 MB
    float4* PSE    = (float4*)w;    w += (size_t)NT * NS * 16;      // 23.4 MB
    _Float16* QT   = (_Float16*)w;  w += (size_t)NT * NSNH * 2;     // 46.7 MB
    float2* BASE12 = (float2*)w;    w += (size_t)NS * HID * 8;      // 4.1 MB
    float* P8      = (float*)w;     w += (size_t)NS * NH * 8 * 4;
    float* RKGA    = (float*)w;     w += (size_t)NS * NH * 16 * 4;
    _Float16* W2H  = (_Float16*)w;  w += 48 * HID * 2;
    float4* CC4    = (float4*)w;    w += HID * 16;
    (void)ws_size; (void)in_sizes; (void)n_in; (void)out_size;

    k_pack<<<dim3(1), dim3(256), 0, stream>>>(T1W1, T2W1, T1W2, T2W2, CC4, W2H);
    k_basin<<<dim3(NS / 4), dim3(256), 0, stream>>>(XC, fcW1, fcb1, fcW2, fcb2,
                                                    fRW1, fRb1, fRW2, fRb2,
                                                    T1W1, T1b1, T2W1, T2b1,
                                                    P8, RKGA, BASE12);
    k_mlp<<<dim3(125, 183), dim3(64), 0, stream>>>(
        X, BASE12, CC4, W2H, T1b2, T2b2, VMK, PSE);
    k_scan<<<dim3(NS / 4), dim3(64), 0, stream>>>(VMK, PSE, P8, QT);
    k_conv<<<dim3(NS, 3), dim3(256), 0, stream>>>(QT, RKGA, OUT);
}

// Round 8
// 547.754 us; speedup vs baseline: 1.5302x; 1.5302x over previous
//
#include <hip/hip_runtime.h>
#include <math.h>

#define NT 730
#define NS 2000
#define NH 16
#define NG 32
#define NR 15
#define HID 256
#define NSNH 32000

// 2*log2(e): pre-folded into BASE12/CC4 so tanh arg is a bare fma
// and tanh(x) = 1 - 2*rcp(exp2(y)+1), y = SC*x.
#define SC 2.885390081777927f
#define INV6 0.16666666666666666f

typedef _Float16 f16x8 __attribute__((ext_vector_type(8)));
typedef __fp16 fp16v2 __attribute__((ext_vector_type(2)));   // cvt_pkrtz native return type
typedef float f32x4 __attribute__((ext_vector_type(4)));

__device__ __forceinline__ float tanh_pre(float y) {   // y = SC * x
    float e = __builtin_amdgcn_exp2f(y);
    float r = __builtin_amdgcn_rcpf(e + 1.f);
    return fmaf(-2.f, r, 1.f);
}
__device__ __forceinline__ float fast_tanh(float x) { return tanh_pre(x * SC); }
__device__ __forceinline__ float sigmoidf_(float x) { return 1.f / (1.f + __expf(-x)); }

__device__ __forceinline__ f16x8 tanh8(float4 lo, float4 hi) {
    union { fp16v2 h[4]; f16x8 v; } u;
    u.h[0] = __builtin_amdgcn_cvt_pkrtz(tanh_pre(lo.x), tanh_pre(lo.y));
    u.h[1] = __builtin_amdgcn_cvt_pkrtz(tanh_pre(lo.z), tanh_pre(lo.w));
    u.h[2] = __builtin_amdgcn_cvt_pkrtz(tanh_pre(hi.x), tanh_pre(hi.y));
    u.h[3] = __builtin_amdgcn_cvt_pkrtz(tanh_pre(hi.z), tanh_pre(hi.w));
    return u.v;
}

// ---------------------------------------------------------------------------
// k_pack: CC4[k] = (SC*a1, SC*c0, SC*c1, SC*c2) interleaved float4.
//   W2H folding: cols 0..31 x1/6 (hsig->clamp); cols 32..47 xSC (exp->exp2).
// ---------------------------------------------------------------------------
__global__ __launch_bounds__(256) void k_pack(
    const float* __restrict__ T1W1, const float* __restrict__ T2W1,
    const float* __restrict__ T1W2, const float* __restrict__ T2W2,
    float4* __restrict__ CC4, _Float16* __restrict__ W2H)
{
    int k = threadIdx.x;
    CC4[k] = make_float4(SC * T1W1[k * (1 + NG)],
                         SC * T2W1[k * (3 + NG)],
                         SC * T2W1[k * (3 + NG) + 1],
                         SC * T2W1[k * (3 + NG) + 2]);
    for (int c = 0; c < 48; ++c) {
        float w = (c < 32) ? (INV6 * T1W2[c * HID + k]) : (SC * T2W2[(c - 32) * HID + k]);
        W2H[c * HID + k] = (_Float16)w;
    }
}

// ---------------------------------------------------------------------------
// k_basin: 4 basins per block; BASE12[s][k] = (SC*b1, SC*b2) interleaved.
// ---------------------------------------------------------------------------
__global__ __launch_bounds__(256) void k_basin(
    const float* __restrict__ XC,
    const float* __restrict__ fcW1, const float* __restrict__ fcb1,
    const float* __restrict__ fcW2, const float* __restrict__ fcb2,
    const float* __restrict__ fRW1, const float* __restrict__ fRb1,
    const float* __restrict__ fRW2, const float* __restrict__ fRb2,
    const float* __restrict__ T1W1, const float* __restrict__ T1b1,
    const float* __restrict__ T2W1, const float* __restrict__ T2b1,
    float* __restrict__ P8, float* __restrict__ RKGA,
    float2* __restrict__ BASE12)
{
    const int s0 = blockIdx.x * 4, tid = threadIdx.x;
    __shared__ float xcs[4][NG];
    __shared__ float h[4][HID], hR[4][HID];
    __shared__ float wbuf[4][10 * NH], wRbuf[4][NH * NR];
    __shared__ float gav[4][NH];

    if (tid < 128) xcs[tid >> 5][tid & 31] = XC[(s0 + (tid >> 5)) * NG + (tid & 31)];
    __syncthreads();

    {
        float ab0 = fcb1[tid], ab1 = ab0, ab2 = ab0, ab3 = ab0;
        float rb0 = fRb1[tid], rb1 = rb0, rb2 = rb0, rb3 = rb0;
        const float4* w4  = (const float4*)(fcW1 + tid * NG);
        const float4* wR4 = (const float4*)(fRW1 + tid * NG);
#pragma unroll
        for (int g = 0; g < NG / 4; ++g) {
            float4 wv = w4[g], rv = wR4[g];
            float4 x0 = *(const float4*)&xcs[0][g * 4];
            float4 x1 = *(const float4*)&xcs[1][g * 4];
            float4 x2 = *(const float4*)&xcs[2][g * 4];
            float4 x3 = *(const float4*)&xcs[3][g * 4];
            ab0 += x0.x*wv.x + x0.y*wv.y + x0.z*wv.z + x0.w*wv.w;
            ab1 += x1.x*wv.x + x1.y*wv.y + x1.z*wv.z + x1.w*wv.w;
            ab2 += x2.x*wv.x + x2.y*wv.y + x2.z*wv.z + x2.w*wv.w;
            ab3 += x3.x*wv.x + x3.y*wv.y + x3.z*wv.z + x3.w*wv.w;
            rb0 += x0.x*rv.x + x0.y*rv.y + x0.z*rv.z + x0.w*rv.w;
            rb1 += x1.x*rv.x + x1.y*rv.y + x1.z*rv.z + x1.w*rv.w;
            rb2 += x2.x*rv.x + x2.y*rv.y + x2.z*rv.z + x2.w*rv.w;
            rb3 += x3.x*rv.x + x3.y*rv.y + x3.z*rv.z + x3.w*rv.w;
        }
        h[0][tid] = fast_tanh(ab0); h[1][tid] = fast_tanh(ab1);
        h[2][tid] = fast_tanh(ab2); h[3][tid] = fast_tanh(ab3);
        hR[0][tid] = fast_tanh(rb0); hR[1][tid] = fast_tanh(rb1);
        hR[2][tid] = fast_tanh(rb2); hR[3][tid] = fast_tanh(rb3);

        float b10 = T1b1[tid], b11 = b10, b12 = b10, b13 = b10;
        float b20 = T2b1[tid], b21 = b20, b22 = b20, b23 = b20;
        const float* w1 = T1W1 + tid * (1 + NG) + 1;
        const float* w2 = T2W1 + tid * (3 + NG) + 3;
#pragma unroll 8
        for (int g = 0; g < NG; ++g) {
            float w1g = w1[g], w2g = w2[g];
            float x0 = xcs[0][g], x1 = xcs[1][g], x2 = xcs[2][g], x3 = xcs[3][g];
            b10 = fmaf(x0, w1g, b10); b11 = fmaf(x1, w1g, b11);
            b12 = fmaf(x2, w1g, b12); b13 = fmaf(x3, w1g, b13);
            b20 = fmaf(x0, w2g, b20); b21 = fmaf(x1, w2g, b21);
            b22 = fmaf(x2, w2g, b22); b23 = fmaf(x3, w2g, b23);
        }
        BASE12[(size_t)(s0 + 0) * HID + tid] = make_float2(SC * b10, SC * b20);
        BASE12[(size_t)(s0 + 1) * HID + tid] = make_float2(SC * b11, SC * b21);
        BASE12[(size_t)(s0 + 2) * HID + tid] = make_float2(SC * b12, SC * b22);
        BASE12[(size_t)(s0 + 3) * HID + tid] = make_float2(SC * b13, SC * b23);
    }
    __syncthreads();

    if (tid < 10 * NH) {
        float a0 = fcb2[tid], a1 = a0, a2 = a0, a3 = a0;
        const float4* w4 = (const float4*)(fcW2 + tid * HID);
        for (int k = 0; k < HID / 4; ++k) {
            float4 wv = w4[k];
            float4 h0 = *(const float4*)&h[0][k * 4];
            float4 h1 = *(const float4*)&h[1][k * 4];
            float4 h2 = *(const float4*)&h[2][k * 4];
            float4 h3 = *(const float4*)&h[3][k * 4];
            a0 += h0.x*wv.x + h0.y*wv.y + h0.z*wv.z + h0.w*wv.w;
            a1 += h1.x*wv.x + h1.y*wv.y + h1.z*wv.z + h1.w*wv.w;
            a2 += h2.x*wv.x + h2.y*wv.y + h2.z*wv.z + h2.w*wv.w;
            a3 += h3.x*wv.x + h3.y*wv.y + h3.z*wv.z + h3.w*wv.w;
        }
        wbuf[0][tid] = a0; wbuf[1][tid] = a1; wbuf[2][tid] = a2; wbuf[3][tid] = a3;
    }
    if (tid < NH * NR) {
        float a0 = fRb2[tid], a1 = a0, a2 = a0, a3 = a0;
        const float4* w4 = (const float4*)(fRW2 + tid * HID);
        for (int k = 0; k < HID / 4; ++k) {
            float4 wv = w4[k];
            float4 h0 = *(const float4*)&hR[0][k * 4];
            float4 h1 = *(const float4*)&hR[1][k * 4];
            float4 h2 = *(const float4*)&hR[2][k * 4];
            float4 h3 = *(const float4*)&hR[3][k * 4];
            a0 += h0.x*wv.x + h0.y*wv.y + h0.z*wv.z + h0.w*wv.w;
            a1 += h1.x*wv.x + h1.y*wv.y + h1.z*wv.z + h1.w*wv.w;
            a2 += h2.x*wv.x + h2.y*wv.y + h2.z*wv.z + h2.w*wv.w;
            a3 += h3.x*wv.x + h3.y*wv.y + h3.z*wv.z + h3.w*wv.w;
        }
        wRbuf[0][tid] = a0; wRbuf[1][tid] = a1; wRbuf[2][tid] = a2; wRbuf[3][tid] = a3;
    }
    __syncthreads();

    if (tid < 64) {
        int b = tid >> 4, hh = tid & 15;
        const float* wb = wbuf[b];
        float mx = -1e30f;
        for (int i = 0; i < NH; ++i) mx = fmaxf(mx, wb[6 * NH + i]);
        float sum = 0.f;
        for (int i = 0; i < NH; ++i) sum += expf(wb[6 * NH + i] - mx);
        gav[b][hh] = expf(wb[6 * NH + hh] - mx) / sum;

        float* p = P8 + (size_t)((s0 + b) * NH + hh) * 8;
        p[0] = sigmoidf_(wb[1 * NH + hh]);
        p[1] = sigmoidf_(wb[2 * NH + hh]);
        p[2] = sigmoidf_(wb[3 * NH + hh]);
        p[3] = sigmoidf_(wb[4 * NH + hh]) * 0.1f;
        p[4] = expf(wb[5 * NH + hh]) * 2.f;
        p[5] = fmaxf(wb[7 * NH + hh], 0.f);
        p[6] = fmaxf(wb[8 * NH + hh], 0.f);
        p[7] = fmaxf(wb[9 * NH + hh], 0.f);
    }
    __syncthreads();

    for (int it = tid; it < 4 * NH * NR; it += 256) {
        int b = it / (NH * NR), r = it % (NH * NR);
        int hh = r / NR, j = r % NR;
        RKGA[(size_t)((s0 + b) * NH + hh) * 16 + (NR - 1 - j)] =
            gav[b][hh] * fmaxf(wRbuf[b][hh * NR + j], 0.f);
    }
}

// ---------------------------------------------------------------------------
// PSE helper (vp partition).
// ---------------------------------------------------------------------------
__device__ __forceinline__ void store_pse(float4* __restrict__ PSE, long m, float2 pe, float2 t12) {
    float P = pe.x, E = pe.y, T1 = t12.x, T2 = t12.y;
    float den = T2 - T1;
    float ratio = (T1 + T2) / ((den == 0.f) ? 1.f : den);
    ratio = fminf(fmaxf(ratio, -1.f), 1.f);
    if ((T1 >= 0.f) || (T2 <= 0.f)) ratio = 0.f;
    float vp = 1.f - acosf(ratio) * (1.f / 3.1415f);
    if (T1 >= 0.f) vp = 1.f;
    if (T2 <= 0.f) vp = 0.f;
    PSE[m] = make_float4(P * (1.f - vp), P * vp, E, 0.f);
}

// ---------------------------------------------------------------------------
// k_mlp v6 (unchanged from R7): one wave per block, t-reuse x4, CC4/BASE12
//   interleaved single-base loads, no private arrays.
// ---------------------------------------------------------------------------
__global__ __launch_bounds__(64) void k_mlp(
    const float* __restrict__ X,
    const float2* __restrict__ BASE12, const float4* __restrict__ CC4,
    const _Float16* __restrict__ W2H,
    const float* __restrict__ T1b2, const float* __restrict__ T2b2,
    uint2* __restrict__ VMK, float4* __restrict__ PSE)
{
    const int lane = threadIdx.x;
    const int quad = lane >> 4, ml = lane & 15;
    const int s0 = blockIdx.x * 16;
    const int t0 = blockIdx.y * 4;
    const int srow = s0 + ml;

    const int tc0 = (t0 < NT) ? t0 : (NT - 1);
    const int tc1 = (t0 + 1 < NT) ? t0 + 1 : (NT - 1);
    const int tc2 = (t0 + 2 < NT) ? t0 + 2 : (NT - 1);
    const int tc3 = (t0 + 3 < NT) ? t0 + 3 : (NT - 1);

    const float* xr0 = X + ((long)tc0 * NS + srow) * 6;
    const float* xr1 = X + ((long)tc1 * NS + srow) * 6;
    const float* xr2 = X + ((long)tc2 * NS + srow) * 6;
    const float* xr3 = X + ((long)tc3 * NS + srow) * 6;
    float2 tt0 = *(const float2*)(xr0 + 2), rl0 = *(const float2*)(xr0 + 4);
    float2 tt1 = *(const float2*)(xr1 + 2), rl1 = *(const float2*)(xr1 + 4);
    float2 tt2 = *(const float2*)(xr2 + 2), rl2 = *(const float2*)(xr2 + 4);
    float2 tt3 = *(const float2*)(xr3 + 2), rl3 = *(const float2*)(xr3 + 4);

    const float bvi = fmaf(T1b2[ml], INV6, 0.5f);
    const float bvk = fmaf(T1b2[NH + ml], INV6, 0.5f);
    const float bvm = SC * T2b2[ml];
    f32x4 ac0_0 = {bvi, bvi, bvi, bvi}, ac0_1 = ac0_0, ac0_2 = ac0_0, ac0_3 = ac0_0;
    f32x4 ac1_0 = {bvk, bvk, bvk, bvk}, ac1_1 = ac1_0, ac1_2 = ac1_0, ac1_3 = ac1_0;
    f32x4 ac2_0 = {bvm, bvm, bvm, bvm}, ac2_1 = ac2_0, ac2_2 = ac2_0, ac2_3 = ac2_0;

    const float2* b12p = BASE12 + (size_t)srow * HID;
    const _Float16* wvi = W2H + (size_t)ml * HID;
    const _Float16* wvk = W2H + (size_t)(NH + ml) * HID;
    const _Float16* wvm = W2H + (size_t)(2 * NH + ml) * HID;

#pragma unroll 2
    for (int ks = 0; ks < 8; ++ks) {
        const int kb = ks * 32 + quad * 8;
        float4 cc0 = CC4[kb], cc1 = CC4[kb + 1], cc2 = CC4[kb + 2], cc3 = CC4[kb + 3];
        float4 cc4 = CC4[kb + 4], cc5 = CC4[kb + 5], cc6 = CC4[kb + 6], cc7 = CC4[kb + 7];
        float4 bA = *(const float4*)(b12p + kb);       // b1[k],b2[k],b1[k+1],b2[k+1]
        float4 bB = *(const float4*)(b12p + kb + 2);
        float4 bC = *(const float4*)(b12p + kb + 4);
        float4 bD = *(const float4*)(b12p + kb + 6);
        f16x8 Bvi = *(const f16x8*)(wvi + kb);
        f16x8 Bvk = *(const f16x8*)(wvk + kb);
        f16x8 Bvm = *(const f16x8*)(wvm + kb);

#define ARG2(CC, B2, TT, RL) fmaf(TT.y, CC.w, fmaf(TT.x, CC.z, fmaf(RL.x, CC.y, B2)))
#define DO_TILE(RL, TT, AC0, AC1, AC2) { \
        float4 a1lo = make_float4(fmaf(RL.y, cc0.x, bA.x), fmaf(RL.y, cc1.x, bA.z), \
                                  fmaf(RL.y, cc2.x, bB.x), fmaf(RL.y, cc3.x, bB.z)); \
        float4 a1hi = make_float4(fmaf(RL.y, cc4.x, bC.x), fmaf(RL.y, cc5.x, bC.z), \
                                  fmaf(RL.y, cc6.x, bD.x), fmaf(RL.y, cc7.x, bD.z)); \
        f16x8 Af1 = tanh8(a1lo, a1hi); \
        float4 a2lo = make_float4(ARG2(cc0, bA.y, TT, RL), ARG2(cc1, bA.w, TT, RL), \
                                  ARG2(cc2, bB.y, TT, RL), ARG2(cc3, bB.w, TT, RL)); \
        float4 a2hi = make_float4(ARG2(cc4, bC.y, TT, RL), ARG2(cc5, bC.w, TT, RL), \
                                  ARG2(cc6, bD.y, TT, RL), ARG2(cc7, bD.w, TT, RL)); \
        f16x8 Af2 = tanh8(a2lo, a2hi); \
        AC0 = __builtin_amdgcn_mfma_f32_16x16x32_f16(Af1, Bvi, AC0, 0, 0, 0); \
        AC1 = __builtin_amdgcn_mfma_f32_16x16x32_f16(Af1, Bvk, AC1, 0, 0, 0); \
        AC2 = __builtin_amdgcn_mfma_f32_16x16x32_f16(Af2, Bvm, AC2, 0, 0, 0); }

        DO_TILE(rl0, tt0, ac0_0, ac1_0, ac2_0)
        DO_TILE(rl1, tt1, ac0_1, ac1_1, ac2_1)
        DO_TILE(rl2, tt2, ac0_2, ac1_2, ac2_2)
        DO_TILE(rl3, tt3, ac0_3, ac1_3, ac2_3)
#undef DO_TILE
#undef ARG2
    }

#define EPI(TC, AC0, AC1, AC2) { \
    long rowbase = (long)TC * NS + s0 + quad * 4; \
    _Pragma("unroll") \
    for (int rg = 0; rg < 4; ++rg) { \
        float vi = fminf(fmaxf(AC0[rg], 0.f), 1.f); \
        float vk = fminf(fmaxf(AC1[rg], 0.f), 1.f); \
        float vm = __builtin_amdgcn_exp2f(AC2[rg]); \
        unsigned pk = (unsigned)(vi * 65535.f + 0.5f) | ((unsigned)(vk * 65535.f + 0.5f) << 16); \
        VMK[(rowbase + rg) * NH + ml] = make_uint2(pk, __float_as_uint(vm)); \
    } }

    EPI(tc0, ac0_0, ac1_0, ac2_0)
    EPI(tc1, ac0_1, ac1_1, ac2_1)
    EPI(tc2, ac0_2, ac1_2, ac2_2)
    EPI(tc3, ac0_3, ac1_3, ac2_3)
#undef EPI

    {
        int tq = t0 + quad; if (tq >= NT) tq = NT - 1;
        const float* xq = X + ((long)tq * NS + srow) * 6;
        float2 peq = *(const float2*)xq;
        float2 ttq = *(const float2*)(xq + 2);
        store_pse(PSE, (long)tq * NS + srow, peq, ttq);
    }
}

// ---------------------------------------------------------------------------
// k_scan v4: recurrence + in-register 15-tap conv per channel (mod-14 ring,
//   constant indices). Stores per-channel conv output YH[t,ch] (fp16) — the
//   h-reduction is deferred to k_reduce. No shuffles in the loop.
// ---------------------------------------------------------------------------
__global__ __launch_bounds__(64) void k_scan(
    const uint2* __restrict__ VMK, const float4* __restrict__ PSE,
    const float* __restrict__ P8, const float* __restrict__ RKGA,
    _Float16* __restrict__ YH)
{
    int lane = threadIdx.x;
    int s = blockIdx.x * 4 + (lane >> 4);
    int hh = lane & 15;
    size_t ch = (size_t)s * NH + hh;

    const float4* pp = (const float4*)(P8 + (size_t)ch * 8);
    float4 pa = pp[0], pb4 = pp[1];
    float k1 = pa.x, k2 = pa.y, k23 = pa.z, k3 = pa.w;
    float gl = pb4.x, qb = pb4.y, ge1 = pb4.z, ge2 = pb4.w;

    float rk[16];
    {
        const float4* rp = (const float4*)(RKGA + (size_t)ch * 16);
#pragma unroll
        for (int i = 0; i < 4; ++i) {
            float4 v = rp[i];
            rk[4 * i] = v.x; rk[4 * i + 1] = v.y; rk[4 * i + 2] = v.z; rk[4 * i + 3] = v.w;
        }
    }

    float S0 = 0.f, Sv = 0.f, S2 = 0.f, S3 = 0.f;
    float qr[14];
#pragma unroll
    for (int i = 0; i < 14; ++i) qr[i] = 0.f;

    uint2 vb[14]; float4 pbf[14];
#pragma unroll
    for (int i = 0; i < 14; ++i) {
        vb[i] = VMK[(size_t)i * NSNH + ch];
        pbf[i] = PSE[(size_t)i * NS + s];
    }

    int t = 0;
#define SBODY(I) { \
    uint2 v = vb[I]; float4 ps = pbf[I]; \
    int t2 = t + 14; if (t2 > NT - 1) t2 = NT - 1; \
    vb[I] = VMK[(size_t)t2 * NSNH + ch]; \
    pbf[I] = PSE[(size_t)t2 * NS + s]; \
    float vi = (float)(v.x & 0xffffu) * (1.f / 65535.f); \
    float vk = (float)(v.x >> 16) * (1.f / 65535.f); \
    float vm = __uint_as_float(v.y); \
    float Ps = ps.x, Pl = ps.y, E = ps.z; \
    float H0 = S0 + Ps; \
    float qSm = fminf(H0, vm); S0 = H0 - qSm; \
    float Hv = fmaxf(Sv + Pl * (1.f - vi) - E * ge1, 0.f); \
    float qv = Sv * vk; Sv = Hv - qv; \
    float H2 = fmaxf(S2 + qSm + qv - E * ge2 + Pl * vi, 0.f); \
    float x1 = H2 - gl; \
    float Q1 = (x1 > 0.f) ? __expf(k1 * __logf(x1)) : 0.f; \
    float q2 = fminf(H2, gl) * k2; \
    float Q2 = q2 * (1.f - k23); \
    float H3 = S3 + q2 * k23; \
    float Q3 = H3 * k3 + qb; \
    S2 = H2 - Q1 - q2; S3 = H3 - Q3; \
    float qt = Q1 + Q2 + Q3; \
    float y = qt * rk[0]; \
    _Pragma("unroll") for (int d = 1; d <= 14; ++d) y += qr[((I) + 14 - d) % 14] * rk[d]; \
    qr[I] = qt; \
    YH[(size_t)t * NSNH + ch] = (_Float16)y; \
    ++t; }

    for (int tb = 0; tb < 52; ++tb) {          // 52 * 14 = 728 steps
        SBODY(0) SBODY(1) SBODY(2) SBODY(3) SBODY(4) SBODY(5) SBODY(6)
        SBODY(7) SBODY(8) SBODY(9) SBODY(10) SBODY(11) SBODY(12) SBODY(13)
    }
    SBODY(0) SBODY(1)                          // steps 728, 729
#undef SBODY
}

// ---------------------------------------------------------------------------
// k_reduce: OUT[t,s] = sum_h YH[t, s*16+h]. One thread per (t,s); 32 B
//   contiguous per lane -> coalesced 2 KB per wave.
// ---------------------------------------------------------------------------
__global__ __launch_bounds__(256) void k_reduce(
    const _Float16* __restrict__ YH, float* __restrict__ OUT)
{
    long m = (long)blockIdx.x * 256 + threadIdx.x;
    if (m >= (long)NT * NS) return;
    int t = (int)(m / NS), s = (int)(m % NS);
    const _Float16* q = YH + (size_t)t * NSNH + (size_t)s * NH;
    f16x8 a = *(const f16x8*)q;
    f16x8 b = *(const f16x8*)(q + 8);
    float acc = 0.f;
#pragma unroll
    for (int i = 0; i < 8; ++i) acc += (float)a[i];
#pragma unroll
    for (int i = 0; i < 8; ++i) acc += (float)b[i];
    OUT[m] = acc;
}

// ---------------------------------------------------------------------------
extern "C" void kernel_launch(void* const* d_in, const int* in_sizes, int n_in,
                              void* d_out, int out_size, void* d_ws, size_t ws_size,
                              hipStream_t stream)
{
    const float* X    = (const float*)d_in[0];
    const float* XC   = (const float*)d_in[1];
    const float* fcW1 = (const float*)d_in[2];
    const float* fcb1 = (const float*)d_in[3];
    const float* fcW2 = (const float*)d_in[4];
    const float* fcb2 = (const float*)d_in[5];
    const float* fRW1 = (const float*)d_in[6];
    const float* fRb1 = (const float*)d_in[7];
    const float* fRW2 = (const float*)d_in[8];
    const float* fRb2 = (const float*)d_in[9];
    const float* T1W1 = (const float*)d_in[10];
    const float* T1b1 = (const float*)d_in[11];
    const float* T1W2 = (const float*)d_in[12];
    const float* T1b2 = (const float*)d_in[13];
    const float* T2W1 = (const float*)d_in[14];
    const float* T2b1 = (const float*)d_in[15];
    const float* T2W2 = (const float*)d_in[16];
    const float* T2b2 = (const float*)d_in[17];
    float* OUT = (float*)d_out;

    char* w = (char*)d_ws;
    uint2* VMK     = (uint2*)w;     w += (size_t)NT * NSNH * 8;     // 186.9 MB
    float4* PSE    = (float4*)w;    w += (size_t)NT * NS * 16;      // 23.4 MB
    _Float16* YH   = (_Float16*)w;  w += (size_t)NT * NSNH * 2;     // 46.7 MB
    float2* BASE12 = (float2*)w;    w += (size_t)NS * HID * 8;      // 4.1 MB
    float* P8      = (float*)w;     w += (size_t)NS * NH * 8 * 4;
    float* RKGA    = (float*)w;     w += (size_t)NS * NH * 16 * 4;
    _Float16* W2H  = (_Float16*)w;  w += 48 * HID * 2;
    float4* CC4    = (float4*)w;    w += HID * 16;
    (void)ws_size; (void)in_sizes; (void)n_in; (void)out_size;

    k_pack<<<dim3(1), dim3(256), 0, stream>>>(T1W1, T2W1, T1W2, T2W2, CC4, W2H);
    k_basin<<<dim3(NS / 4), dim3(256), 0, stream>>>(XC, fcW1, fcb1, fcW2, fcb2,
                                                    fRW1, fRb1, fRW2, fRb2,
                                                    T1W1, T1b1, T2W1, T2b1,
                                                    P8, RKGA, BASE12);
    k_mlp<<<dim3(125, 183), dim3(64), 0, stream>>>(
        X, BASE12, CC4, W2H, T1b2, T2b2, VMK, PSE);
    k_scan<<<dim3(NS / 4), dim3(64), 0, stream>>>(VMK, PSE, P8, RKGA, YH);
    k_reduce<<<dim3((unsigned)(((long)NT * NS + 255) / 256)), dim3(256), 0, stream>>>(YH, OUT);
}